// Round 12
// baseline (179.058 us; speedup 1.0000x reference)
//
#include <hip/hip_runtime.h>

#define IN_    16
#define HID_   50
#define T_     128
#define NCLS_  20
#define BPB_   8      // batches per block (N=8 of 16 MFMA cols used)
#define NTHR_  512    // 8 waves: 7 compute (2 M-tiles each) + 1 x-loader
#define NTILE_ 14     // 14 tiles x 16 slots = 224 gate-slots (200 real)
#define NQ_    2      // K chunks of 32 -> K=64 MFMA; rows 64,65 via fdot2 tail
#define KP_    72     // state row stride in halves (144B, 16B-aligned)
#define KPW_   36     // state row stride in u32

typedef _Float16 half8 __attribute__((ext_vector_type(8)));
typedef _Float16 h2_t  __attribute__((ext_vector_type(2)));
typedef float    f32x4 __attribute__((ext_vector_type(4)));
typedef unsigned int u32;

#define L2E_ 1.4426950408889634f
__device__ __forceinline__ h2_t as_h2(u32 v) { union { u32 u; h2_t h; } x; x.u = v; return x.h; }
__device__ __forceinline__ u32 pkh2(float a, float b) {
    union { u32 v; _Float16 h[2]; } p; p.h[0] = (_Float16)a; p.h[1] = (_Float16)b; return p.v;
}
#define FDOT2(S, W, ACC) __builtin_amdgcn_fdot2(as_h2(S), as_h2(W), (ACC), false)
#define MFMA(A, B, C) __builtin_amdgcn_mfma_f32_16x16x32_f16((A), (B), (C), 0, 0, 0)
// activation-domain helpers (weights PRE-SCALED by -log2e / -2log2e)
#define SIGS(v)  __builtin_amdgcn_rcpf(1.0f + __builtin_amdgcn_exp2f(v))
#define TANHS(v) fmaf(2.0f, __builtin_amdgcn_rcpf(1.0f + __builtin_amdgcn_exp2f(v)), -1.0f)

// (512, 8 waves/EU) -> VGPR cap 64, demand ~60 -> 4 blocks/CU = 4 independent
// barrier domains (latency hiding). FETCH_SIZE is the spill tripwire (R5).
__global__ __launch_bounds__(NTHR_, 8)
void lstm_mfma(const float* __restrict__ x,
               const float* __restrict__ W_ih,
               const float* __restrict__ W_hh,
               const float* __restrict__ b_ih,
               const float* __restrict__ b_hh,
               const float* __restrict__ W_fc,
               const float* __restrict__ b_fc,
               float* __restrict__ out)
{
    // weight A-fragments (K rows 0..63), fragment-linear; dead after reg preload
    __shared__ __align__(16) _Float16 wfrag[NTILE_ * NQ_ * 64 * 8];  // 28.7 KB
    // state ping-pong: st[buf][batch*KP_ + k]; k 0..15 = x, 16..65 = h, 66..71 = 0
    __shared__ __align__(16) _Float16 st[2][BPB_ * KP_];             // 2.3 KB

    const int tid  = threadIdx.x;
    const int lane = tid & 63;
    const int wv   = tid >> 6;          // 0..7
    const int b0   = blockIdx.x * BPB_;

    // ---- stage weight fragments, PRE-SCALED into activation domain.
    //      slot s = 4u+kk; A row (M) = lane&15, k = (lane>>4)*8 + e.
    u32* wf32 = (u32*)wfrag;
    for (int idx = tid; idx < NTILE_ * NQ_ * 256; idx += NTHR_) {
        const int j    = idx & 3;
        const int ln   = (idx >> 2) & 63;
        const int chnk = idx >> 8;                 // tile*2 + q
        const int tile = chnk >> 1, q = chnk & 1;
        const int s  = tile * 16 + (ln & 15);
        const int u_ = s >> 2, kk = s & 3;
        const int k0 = q * 32 + (ln >> 4) * 8 + 2 * j;
        float w0 = 0.f, w1 = 0.f;
        if (u_ < HID_) {
            const int g = kk * HID_ + u_;
            w0 = (k0 < IN_) ? W_ih[g * IN_ + k0] : W_hh[g * HID_ + (k0 - IN_)];
            w1 = (k0 + 1 < IN_) ? W_ih[g * IN_ + k0 + 1] : W_hh[g * HID_ + (k0 + 1 - IN_)];
        }
        const float sc_ = (kk == 2) ? (-2.0f * L2E_) : (-L2E_);
        wf32[idx] = pkh2(w0 * sc_, w1 * sc_);
    }
    // ---- zero both state buffers (h(0)=0; pad rows stay 0 forever)
    for (int idx = tid; idx < 2 * BPB_ * KPW_; idx += NTHR_)
        ((u32*)st)[idx] = 0u;

    // ---- compute waves 0..6: tiles 2wv, 2wv+1 -> units u0 = 8wv+(lane>>4), u1 = u0+4
    const bool comp = (wv < 7);
    const int  u0   = 8 * wv + (lane >> 4);
    const int  u1   = u0 + 4;
    f32x4 bias0 = {0.f,0.f,0.f,0.f}, bias1 = {0.f,0.f,0.f,0.f};
    u32 ta0=0,ta1=0,ta2=0,ta3=0, tb0=0,tb1=0,tb2=0,tb3=0;   // scaled tail wts (K 64,65)
    if (comp && u0 < HID_) {
        bias0[0] = (b_ih[u0         ] + b_hh[u0         ]) * -L2E_;
        bias0[1] = (b_ih[HID_  + u0 ] + b_hh[HID_  + u0 ]) * -L2E_;
        bias0[2] = (b_ih[2*HID_+ u0 ] + b_hh[2*HID_+ u0 ]) * (-2.0f * L2E_);
        bias0[3] = (b_ih[3*HID_+ u0 ] + b_hh[3*HID_+ u0 ]) * -L2E_;
        ta0 = pkh2(W_hh[(u0         ) * HID_ + 48] * -L2E_,          W_hh[(u0         ) * HID_ + 49] * -L2E_);
        ta1 = pkh2(W_hh[(HID_  + u0 ) * HID_ + 48] * -L2E_,          W_hh[(HID_  + u0 ) * HID_ + 49] * -L2E_);
        ta2 = pkh2(W_hh[(2*HID_+ u0 ) * HID_ + 48] * (-2.0f * L2E_), W_hh[(2*HID_+ u0 ) * HID_ + 49] * (-2.0f * L2E_));
        ta3 = pkh2(W_hh[(3*HID_+ u0 ) * HID_ + 48] * -L2E_,          W_hh[(3*HID_+ u0 ) * HID_ + 49] * -L2E_);
    }
    if (comp && u1 < HID_) {
        bias1[0] = (b_ih[u1         ] + b_hh[u1         ]) * -L2E_;
        bias1[1] = (b_ih[HID_  + u1 ] + b_hh[HID_  + u1 ]) * -L2E_;
        bias1[2] = (b_ih[2*HID_+ u1 ] + b_hh[2*HID_+ u1 ]) * (-2.0f * L2E_);
        bias1[3] = (b_ih[3*HID_+ u1 ] + b_hh[3*HID_+ u1 ]) * -L2E_;
        tb0 = pkh2(W_hh[(u1         ) * HID_ + 48] * -L2E_,          W_hh[(u1         ) * HID_ + 49] * -L2E_);
        tb1 = pkh2(W_hh[(HID_  + u1 ) * HID_ + 48] * -L2E_,          W_hh[(HID_  + u1 ) * HID_ + 49] * -L2E_);
        tb2 = pkh2(W_hh[(2*HID_+ u1 ) * HID_ + 48] * (-2.0f * L2E_), W_hh[(2*HID_+ u1 ) * HID_ + 49] * (-2.0f * L2E_));
        tb3 = pkh2(W_hh[(3*HID_+ u1 ) * HID_ + 48] * -L2E_,          W_hh[(3*HID_+ u1 ) * HID_ + 49] * -L2E_);
    }
    float c0_ = 0.f, c1_ = 0.f;

    const int  bcol = lane & 7;                          // batches 0..7 (cols 8-15 dup)
    const int  brow = bcol * KP_ + (lane >> 4) * 8;      // B-fragment half index
    const int  trow = bcol * KPW_ + 32;                  // u32 idx of K rows 64,65
    const bool wrt  = ((lane & 8) == 0);                 // dedupe h writeback
    const int  hrow0 = bcol * KP_ + IN_ + u0;
    const int  hrow1 = bcol * KP_ + IN_ + u1;
    const _Float16* wbase = wfrag + (size_t)(4 * wv) * 512 + lane * 8;

    // ---- loader wave (wv==7): 64 lanes = 8 batches x 8 feature-pairs
    const int bq = lane >> 3, fq = lane & 7;
    const float* xq = x + (size_t)(b0 + bq) * (T_ * IN_) + 2 * fq;
    const int xo = bq * KPW_ + fq;

    __syncthreads();                  // staging + zeros visible

    // A-fragments -> VGPRs once (weights loop-invariant)
    half8 A0 = {}, A1 = {}, A2 = {}, A3 = {};
    if (comp) {
        A0 = *(const half8*)(wbase);
        A1 = *(const half8*)(wbase + 512);
        A2 = *(const half8*)(wbase + 1024);
        A3 = *(const half8*)(wbase + 1536);
    }
    // loader: x(0) -> LDS, x(1) -> regs (global latency stays off the chain)
    float2 xr = make_float2(0.f, 0.f);
    if (!comp) {
        const float2 v = *(const float2*)xq;
        ((u32*)st[0])[xo] = pkh2(v.x, v.y);
        xr = *(const float2*)(xq + IN_);
    }
    __syncthreads();                  // x(0) ready

    for (int t = 0; t < T_; ++t) {
        const _Float16* sc = st[t & 1];
        _Float16*       sn = st[(t & 1) ^ 1];

        if (comp) {
            const half8 B0 = *(const half8*)(sc + brow);
            const half8 B1 = *(const half8*)(sc + brow + 32);
            const u32   hT = ((const u32*)sc)[trow];
            f32x4 C0 = MFMA(A0, B0, bias0);
            C0 = MFMA(A1, B1, C0);
            f32x4 C1 = MFMA(A2, B0, bias1);
            C1 = MFMA(A3, B1, C1);
            C0[0] = FDOT2(hT, ta0, C0[0]);
            C0[1] = FDOT2(hT, ta1, C0[1]);
            C0[2] = FDOT2(hT, ta2, C0[2]);
            C0[3] = FDOT2(hT, ta3, C0[3]);
            C1[0] = FDOT2(hT, tb0, C1[0]);
            C1[1] = FDOT2(hT, tb1, C1[1]);
            C1[2] = FDOT2(hT, tb2, C1[2]);
            C1[3] = FDOT2(hT, tb3, C1[3]);

            {   // tile a
                const float iv = SIGS(C0[0]), fv = SIGS(C0[1]);
                const float gv = TANHS(C0[2]), ov = SIGS(C0[3]);
                c0_ = fmaf(fv, c0_, iv * gv);
                const float hv = ov * TANHS(c0_ * (-2.0f * L2E_));
                if (wrt && u0 < HID_) sn[hrow0] = (_Float16)hv;
            }
            {   // tile b
                const float iv = SIGS(C1[0]), fv = SIGS(C1[1]);
                const float gv = TANHS(C1[2]), ov = SIGS(C1[3]);
                c1_ = fmaf(fv, c1_, iv * gv);
                const float hv = ov * TANHS(c1_ * (-2.0f * L2E_));
                if (wrt && u1 < HID_) sn[hrow1] = (_Float16)hv;
            }
        } else {
            if (t + 1 < T_) ((u32*)sn)[xo] = pkh2(xr.x, xr.y);   // from regs: cheap
            if (t + 2 < T_) xr = *(const float2*)(xq + (size_t)(t + 2) * IN_);
        }
        __syncthreads();              // ONE barrier per step
    }

    // final h in st[0] (t=127 wrote buffer 0), fp16 rows 16..65
    const _Float16* hf = st[0];

    // ---- FC head: 8 batches x 20 classes (160 threads)
    if (tid < BPB_ * NCLS_) {
        const int b  = tid / NCLS_;
        const int cl = tid - b * NCLS_;
        float acc = b_fc[cl];
        #pragma unroll
        for (int j = 0; j < HID_; ++j) {
            const float hv = fmaxf((float)hf[b * KP_ + IN_ + j], 0.0f);   // relu
            acc = fmaf(hv, W_fc[cl * HID_ + j], acc);
        }
        out[(size_t)(b0 + b) * NCLS_ + cl] = acc;
    }
}

extern "C" void kernel_launch(void* const* d_in, const int* in_sizes, int n_in,
                              void* d_out, int out_size, void* d_ws, size_t ws_size,
                              hipStream_t stream) {
    const float* x    = (const float*)d_in[0];
    const float* W_ih = (const float*)d_in[1];
    const float* W_hh = (const float*)d_in[2];
    const float* b_ih = (const float*)d_in[3];
    const float* b_hh = (const float*)d_in[4];
    const float* W_fc = (const float*)d_in[5];
    const float* b_fc = (const float*)d_in[6];
    float* out = (float*)d_out;

    const int B = in_sizes[0] / (T_ * IN_);   // 8192
    dim3 grid(B / BPB_), block(NTHR_);
    hipLaunchKernelGGL(lstm_mfma, grid, block, 0, stream,
                       x, W_ih, W_hh, b_ih, b_hh, W_fc, b_fc, out);
}

// Round 13
// 110.049 us; speedup vs baseline: 1.6271x; 1.6271x over previous
//
#include <hip/hip_runtime.h>

#define IN_    16
#define HID_   50
#define T_     128
#define NCLS_  20
#define BPB_   16     // batches per block = full MFMA N
#define NTHR_  512    // 8 waves: 7 compute (2 M-tiles each) + 1 x-loader
#define NTILE_ 14     // 14 tiles x 16 slots = 224 gate-slots (200 real)
#define NQ_    2      // K chunks of 32 -> K=64 MFMA; rows 64,65 via fdot2 tail
#define KP_    72     // state row stride in halves (144B, 16B-aligned)
#define KPW_   36     // state row stride in u32

typedef _Float16 half8 __attribute__((ext_vector_type(8)));
typedef _Float16 h2_t  __attribute__((ext_vector_type(2)));
typedef float    f32x4 __attribute__((ext_vector_type(4)));
typedef unsigned int u32;

#define L2E_ 1.4426950408889634f
__device__ __forceinline__ h2_t as_h2(u32 v) { union { u32 u; h2_t h; } x; x.u = v; return x.h; }
__device__ __forceinline__ u32 pkh2(float a, float b) {
    union { u32 v; _Float16 h[2]; } p; p.h[0] = (_Float16)a; p.h[1] = (_Float16)b; return p.v;
}
#define FDOT2(S, W, ACC) __builtin_amdgcn_fdot2(as_h2(S), as_h2(W), (ACC), false)
#define MFMA(A, B, C) __builtin_amdgcn_mfma_f32_16x16x32_f16((A), (B), (C), 0, 0, 0)
// activation-domain helpers (weights PRE-SCALED by -log2e / -2log2e)
#define SIGS(v)  __builtin_amdgcn_rcpf(1.0f + __builtin_amdgcn_exp2f(v))
#define TANHS(v) fmaf(2.0f, __builtin_amdgcn_rcpf(1.0f + __builtin_amdgcn_exp2f(v)), -1.0f)

// (512, 6 waves/EU) -> VGPR cap ~85: fits the 2-tile wave's ~75-reg demand
// WITHOUT spilling (R12 died at the 64-cap). 3 blocks/CU = 3 barrier domains,
// 48 batches/CU. FETCH_SIZE + VGPR_Count are the spill tripwires.
__global__ __launch_bounds__(NTHR_, 6)
void lstm_mfma(const float* __restrict__ x,
               const float* __restrict__ W_ih,
               const float* __restrict__ W_hh,
               const float* __restrict__ b_ih,
               const float* __restrict__ b_hh,
               const float* __restrict__ W_fc,
               const float* __restrict__ b_fc,
               float* __restrict__ out)
{
    // weight A-fragments (K rows 0..63), fragment-linear; dead after reg preload
    __shared__ __align__(16) _Float16 wfrag[NTILE_ * NQ_ * 64 * 8];  // 28.7 KB
    // state ping-pong: st[buf][batch*KP_ + k]; k 0..15 = x, 16..65 = h, 66..71 = 0
    __shared__ __align__(16) _Float16 st[2][BPB_ * KP_];             // 4.6 KB

    const int tid  = threadIdx.x;
    const int lane = tid & 63;
    const int wv   = tid >> 6;          // 0..7
    const int b0   = blockIdx.x * BPB_;

    // ---- stage weight fragments, PRE-SCALED into activation domain.
    //      slot s = 4u+kk; A row (M) = lane&15, k = (lane>>4)*8 + e.
    u32* wf32 = (u32*)wfrag;
    for (int idx = tid; idx < NTILE_ * NQ_ * 256; idx += NTHR_) {
        const int j    = idx & 3;
        const int ln   = (idx >> 2) & 63;
        const int chnk = idx >> 8;                 // tile*2 + q
        const int tile = chnk >> 1, q = chnk & 1;
        const int s  = tile * 16 + (ln & 15);
        const int u_ = s >> 2, kk = s & 3;
        const int k0 = q * 32 + (ln >> 4) * 8 + 2 * j;
        float w0 = 0.f, w1 = 0.f;
        if (u_ < HID_) {
            const int g = kk * HID_ + u_;
            w0 = (k0 < IN_) ? W_ih[g * IN_ + k0] : W_hh[g * HID_ + (k0 - IN_)];
            w1 = (k0 + 1 < IN_) ? W_ih[g * IN_ + k0 + 1] : W_hh[g * HID_ + (k0 + 1 - IN_)];
        }
        const float sc_ = (kk == 2) ? (-2.0f * L2E_) : (-L2E_);
        wf32[idx] = pkh2(w0 * sc_, w1 * sc_);
    }
    // ---- zero both state buffers (h(0)=0; pad rows stay 0 forever)
    for (int idx = tid; idx < 2 * BPB_ * KPW_; idx += NTHR_)
        ((u32*)st)[idx] = 0u;

    // ---- compute waves 0..6: tiles 2wv, 2wv+1 -> units u0 = 8wv+(lane>>4), u1 = u0+4
    const bool comp = (wv < 7);
    const int  u0   = 8 * wv + (lane >> 4);
    const int  u1   = u0 + 4;
    f32x4 bias0 = {0.f,0.f,0.f,0.f}, bias1 = {0.f,0.f,0.f,0.f};
    u32 ta0=0,ta1=0,ta2=0,ta3=0, tb0=0,tb1=0,tb2=0,tb3=0;   // scaled tail wts (K 64,65)
    if (comp && u0 < HID_) {
        bias0[0] = (b_ih[u0         ] + b_hh[u0         ]) * -L2E_;
        bias0[1] = (b_ih[HID_  + u0 ] + b_hh[HID_  + u0 ]) * -L2E_;
        bias0[2] = (b_ih[2*HID_+ u0 ] + b_hh[2*HID_+ u0 ]) * (-2.0f * L2E_);
        bias0[3] = (b_ih[3*HID_+ u0 ] + b_hh[3*HID_+ u0 ]) * -L2E_;
        ta0 = pkh2(W_hh[(u0         ) * HID_ + 48] * -L2E_,          W_hh[(u0         ) * HID_ + 49] * -L2E_);
        ta1 = pkh2(W_hh[(HID_  + u0 ) * HID_ + 48] * -L2E_,          W_hh[(HID_  + u0 ) * HID_ + 49] * -L2E_);
        ta2 = pkh2(W_hh[(2*HID_+ u0 ) * HID_ + 48] * (-2.0f * L2E_), W_hh[(2*HID_+ u0 ) * HID_ + 49] * (-2.0f * L2E_));
        ta3 = pkh2(W_hh[(3*HID_+ u0 ) * HID_ + 48] * -L2E_,          W_hh[(3*HID_+ u0 ) * HID_ + 49] * -L2E_);
    }
    if (comp && u1 < HID_) {
        bias1[0] = (b_ih[u1         ] + b_hh[u1         ]) * -L2E_;
        bias1[1] = (b_ih[HID_  + u1 ] + b_hh[HID_  + u1 ]) * -L2E_;
        bias1[2] = (b_ih[2*HID_+ u1 ] + b_hh[2*HID_+ u1 ]) * (-2.0f * L2E_);
        bias1[3] = (b_ih[3*HID_+ u1 ] + b_hh[3*HID_+ u1 ]) * -L2E_;
        tb0 = pkh2(W_hh[(u1         ) * HID_ + 48] * -L2E_,          W_hh[(u1         ) * HID_ + 49] * -L2E_);
        tb1 = pkh2(W_hh[(HID_  + u1 ) * HID_ + 48] * -L2E_,          W_hh[(HID_  + u1 ) * HID_ + 49] * -L2E_);
        tb2 = pkh2(W_hh[(2*HID_+ u1 ) * HID_ + 48] * (-2.0f * L2E_), W_hh[(2*HID_+ u1 ) * HID_ + 49] * (-2.0f * L2E_));
        tb3 = pkh2(W_hh[(3*HID_+ u1 ) * HID_ + 48] * -L2E_,          W_hh[(3*HID_+ u1 ) * HID_ + 49] * -L2E_);
    }
    float c0_ = 0.f, c1_ = 0.f;

    const int bcol = lane & 15;                          // batch column (full 16)
    const int brow = bcol * KP_ + (lane >> 4) * 8;       // B-fragment half index
    const int trow = bcol * KPW_ + 32;                   // u32 idx of K rows 64,65
    const int hrow0 = bcol * KP_ + IN_ + u0;             // h writeback (all lanes distinct)
    const int hrow1 = bcol * KP_ + IN_ + u1;
    const _Float16* wbase = wfrag + (size_t)(4 * wv) * 512 + lane * 8;

    // ---- loader wave (wv==7): 64 lanes = 16 batches x 4 feature-quads
    const int bq = lane >> 2, fq = lane & 3;
    const float* xq = x + (size_t)(b0 + bq) * (T_ * IN_) + 4 * fq;
    const int xo = bq * KPW_ + 2 * fq;

    __syncthreads();                  // staging + zeros visible

    // A-fragments -> VGPRs once (weights loop-invariant)
    half8 A0 = {}, A1 = {}, A2 = {}, A3 = {};
    if (comp) {
        A0 = *(const half8*)(wbase);
        A1 = *(const half8*)(wbase + 512);
        A2 = *(const half8*)(wbase + 1024);
        A3 = *(const half8*)(wbase + 1536);
    }
    // loader: x(0) -> LDS, x(1) -> regs (global latency stays off the chain)
    float4 xr = make_float4(0.f, 0.f, 0.f, 0.f);
    if (!comp) {
        const float4 v = *(const float4*)xq;
        ((u32*)st[0])[xo    ] = pkh2(v.x, v.y);
        ((u32*)st[0])[xo + 1] = pkh2(v.z, v.w);
        xr = *(const float4*)(xq + IN_);
    }
    __syncthreads();                  // x(0) ready

    for (int t = 0; t < T_; ++t) {
        const _Float16* sc = st[t & 1];
        _Float16*       sn = st[(t & 1) ^ 1];

        if (comp) {
            const half8 B0 = *(const half8*)(sc + brow);
            const half8 B1 = *(const half8*)(sc + brow + 32);
            const u32   hT = ((const u32*)sc)[trow];
            f32x4 C0 = MFMA(A0, B0, bias0);
            C0 = MFMA(A1, B1, C0);
            f32x4 C1 = MFMA(A2, B0, bias1);
            C1 = MFMA(A3, B1, C1);
            C0[0] = FDOT2(hT, ta0, C0[0]);
            C0[1] = FDOT2(hT, ta1, C0[1]);
            C0[2] = FDOT2(hT, ta2, C0[2]);
            C0[3] = FDOT2(hT, ta3, C0[3]);
            C1[0] = FDOT2(hT, tb0, C1[0]);
            C1[1] = FDOT2(hT, tb1, C1[1]);
            C1[2] = FDOT2(hT, tb2, C1[2]);
            C1[3] = FDOT2(hT, tb3, C1[3]);

            {   // tile a
                const float iv = SIGS(C0[0]), fv = SIGS(C0[1]);
                const float gv = TANHS(C0[2]), ov = SIGS(C0[3]);
                c0_ = fmaf(fv, c0_, iv * gv);
                const float hv = ov * TANHS(c0_ * (-2.0f * L2E_));
                if (u0 < HID_) sn[hrow0] = (_Float16)hv;
            }
            {   // tile b
                const float iv = SIGS(C1[0]), fv = SIGS(C1[1]);
                const float gv = TANHS(C1[2]), ov = SIGS(C1[3]);
                c1_ = fmaf(fv, c1_, iv * gv);
                const float hv = ov * TANHS(c1_ * (-2.0f * L2E_));
                if (u1 < HID_) sn[hrow1] = (_Float16)hv;
            }
        } else {
            if (t + 1 < T_) {   // from regs: global latency off the chain
                ((u32*)sn)[xo    ] = pkh2(xr.x, xr.y);
                ((u32*)sn)[xo + 1] = pkh2(xr.z, xr.w);
            }
            if (t + 2 < T_) xr = *(const float4*)(xq + (size_t)(t + 2) * IN_);
        }
        __syncthreads();              // ONE barrier per step
    }

    // final h in st[0] (t=127 wrote buffer 0), fp16 rows 16..65
    const _Float16* hf = st[0];

    // ---- FC head: 16 batches x 20 classes (320 threads)
    if (tid < BPB_ * NCLS_) {
        const int b  = tid / NCLS_;
        const int cl = tid - b * NCLS_;
        float acc = b_fc[cl];
        #pragma unroll
        for (int j = 0; j < HID_; ++j) {
            const float hv = fmaxf((float)hf[b * KP_ + IN_ + j], 0.0f);   // relu
            acc = fmaf(hv, W_fc[cl * HID_ + j], acc);
        }
        out[(size_t)(b0 + b) * NCLS_ + cl] = acc;
    }
}

extern "C" void kernel_launch(void* const* d_in, const int* in_sizes, int n_in,
                              void* d_out, int out_size, void* d_ws, size_t ws_size,
                              hipStream_t stream) {
    const float* x    = (const float*)d_in[0];
    const float* W_ih = (const float*)d_in[1];
    const float* W_hh = (const float*)d_in[2];
    const float* b_ih = (const float*)d_in[3];
    const float* b_hh = (const float*)d_in[4];
    const float* W_fc = (const float*)d_in[5];
    const float* b_fc = (const float*)d_in[6];
    float* out = (float*)d_out;

    const int B = in_sizes[0] / (T_ * IN_);   // 8192
    dim3 grid(B / BPB_), block(NTHR_);
    hipLaunchKernelGGL(lstm_mfma, grid, block, 0, stream,
                       x, W_ih, W_hh, b_ih, b_hh, W_fc, b_fc, out);
}

// Round 14
// 107.880 us; speedup vs baseline: 1.6598x; 1.0201x over previous
//
#include <hip/hip_runtime.h>

#define IN_    16
#define HID_   50
#define T_     128
#define NCLS_  20
#define GRP_   16     // batches per group = MFMA N
#define NGRP_  2      // groups per block (two independent chains per wave)
#define BPB_   (GRP_ * NGRP_)   // 32 batches/block -> grid 256 = 1 block/CU
#define NTHR_  896    // 14 waves: 13 compute (1 M-tile each) + 1 x-loader
#define KP_    72     // state row stride in halves (144B, 16B-aligned)
#define KPW_   36     // state row stride in u32

typedef _Float16 half8 __attribute__((ext_vector_type(8)));
typedef _Float16 h2_t  __attribute__((ext_vector_type(2)));
typedef float    f32x4 __attribute__((ext_vector_type(4)));
typedef unsigned int u32;

#define L2E_ 1.4426950408889634f
__device__ __forceinline__ h2_t as_h2(u32 v) { union { u32 u; h2_t h; } x; x.u = v; return x.h; }
__device__ __forceinline__ u32 pkh2(float a, float b) {
    union { u32 v; _Float16 h[2]; } p; p.h[0] = (_Float16)a; p.h[1] = (_Float16)b; return p.v;
}
#define FDOT2(S, W, ACC) __builtin_amdgcn_fdot2(as_h2(S), as_h2(W), (ACC), false)
#define MFMA(A, B, C) __builtin_amdgcn_mfma_f32_16x16x32_f16((A), (B), (C), 0, 0, 0)
// activation-domain helpers (weights PRE-SCALED by -log2e / -2log2e)
#define SIGS(v)  __builtin_amdgcn_rcpf(1.0f + __builtin_amdgcn_exp2f(v))
#define TANHS(v) fmaf(2.0f, __builtin_amdgcn_rcpf(1.0f + __builtin_amdgcn_exp2f(v)), -1.0f)

// (896, 4 waves/EU) -> 128-VGPR cap: fits ~75-reg demand with headroom.
// Avoids BOTH failure modes seen so far: R12's 64-cap spill and R5's
// occupancy-chasing allocator. FETCH_SIZE + VGPR_Count are the tripwires.
__global__ __launch_bounds__(NTHR_, 4)
void lstm_mfma(const float* __restrict__ x,
               const float* __restrict__ W_ih,
               const float* __restrict__ W_hh,
               const float* __restrict__ b_ih,
               const float* __restrict__ b_hh,
               const float* __restrict__ W_fc,
               const float* __restrict__ b_fc,
               float* __restrict__ out)
{
    // state only (weights live in VGPRs, loaded straight from global):
    // st[group][buf][batch*KP_ + k]; k 0..15 = x, 16..65 = h, 66..71 = 0 pad
    __shared__ __align__(16) _Float16 st[NGRP_][2][GRP_ * KP_];   // 9.2 KB

    const int tid  = threadIdx.x;
    const int lane = tid & 63;
    const int wv   = tid >> 6;          // 0..13
    const int b0   = blockIdx.x * BPB_;
    const bool comp = (wv < 13);

    // ---- zero all state buffers (h(0)=0; K-pad rows must stay 0)
    for (int idx = tid; idx < NGRP_ * 2 * GRP_ * KPW_; idx += NTHR_)
        ((u32*)st)[idx] = 0u;

    // ---- A-fragments straight from global -> VGPRs (one time, even-offset
    //      float2 loads; pre-scaled into activation domain).
    //      A M-row slot sA = wv*16 + (lane&15); k-slice (lane>>4)*8.
    half8 A0 = {}, A1 = {};
    if (comp) {
        const int sA = wv * 16 + (lane & 15);
        const int uA = sA >> 2, kA = sA & 3;
        if (uA < HID_) {
            const float scA = (kA == 2) ? (-2.0f * L2E_) : (-L2E_);
            const int g  = kA * HID_ + uA;
            const int k0 = (lane >> 4) * 8;                       // 0,8,16,24
            const float* s0 = (k0 < IN_) ? (W_ih + g * IN_ + k0)
                                         : (W_hh + g * HID_ + (k0 - IN_));
            const float* s1 = W_hh + g * HID_ + 16 + (lane >> 4) * 8;  // k=32..63
            #pragma unroll
            for (int e = 0; e < 4; ++e) {
                const float2 p0 = *(const float2*)(s0 + 2 * e);
                const float2 p1 = *(const float2*)(s1 + 2 * e);
                A0[2*e] = (_Float16)(p0.x * scA); A0[2*e+1] = (_Float16)(p0.y * scA);
                A1[2*e] = (_Float16)(p1.x * scA); A1[2*e+1] = (_Float16)(p1.y * scA);
            }
        }
    }

    // ---- per-lane unit (C/D rows (lane>>4)*4+reg): bias + K-tail weights
    const int u = comp ? (4 * wv + (lane >> 4)) : 0;   // [0,51]; 50,51 pad
    f32x4 bias = {0.f, 0.f, 0.f, 0.f};
    u32 wt0 = 0, wt1 = 0, wt2 = 0, wt3 = 0;            // scaled tails (K 64,65)
    if (comp && u < HID_) {
        bias[0] = (b_ih[u          ] + b_hh[u          ]) * -L2E_;
        bias[1] = (b_ih[HID_   + u ] + b_hh[HID_   + u ]) * -L2E_;
        bias[2] = (b_ih[2*HID_ + u ] + b_hh[2*HID_ + u ]) * (-2.0f * L2E_);
        bias[3] = (b_ih[3*HID_ + u ] + b_hh[3*HID_ + u ]) * -L2E_;
        wt0 = pkh2(W_hh[(u          ) * HID_ + 48] * -L2E_,          W_hh[(u          ) * HID_ + 49] * -L2E_);
        wt1 = pkh2(W_hh[(HID_   + u ) * HID_ + 48] * -L2E_,          W_hh[(HID_   + u ) * HID_ + 49] * -L2E_);
        wt2 = pkh2(W_hh[(2*HID_ + u ) * HID_ + 48] * (-2.0f * L2E_), W_hh[(2*HID_ + u ) * HID_ + 49] * (-2.0f * L2E_));
        wt3 = pkh2(W_hh[(3*HID_ + u ) * HID_ + 48] * -L2E_,          W_hh[(3*HID_ + u ) * HID_ + 49] * -L2E_);
    }
    float cA = 0.f, cB = 0.f;                          // cell state per group

    const int bcol = lane & 15;
    const int brow = bcol * KP_ + (lane >> 4) * 8;     // B-frag half index
    const int trow = bcol * KPW_ + 32;                 // u32 idx of K rows 64,65
    const int hrow = bcol * KP_ + IN_ + u;             // h writeback

    // ---- loader wave (wv==13): lane -> batch lb = lane>>1, feat-half lfh
    const int  lb  = lane >> 1;                        // 0..31
    const int  lg  = lb >> 4;                          // group
    const int  lbc = lb & 15;
    const int  lfh = (lane & 1) * 8;                   // feats lfh..lfh+7
    const float* xq = x + (size_t)(b0 + lb) * (T_ * IN_) + lfh;
    const int  xo  = lbc * KPW_ + (lfh >> 1);          // u32 index in group buf

    float4 xr0 = {0,0,0,0}, xr1 = {0,0,0,0};
    __syncthreads();                                   // zeros visible
    if (!comp) {
        // x(0) -> LDS now; x(1) -> regs (global latency off the chain)
        const float4 v0 = *(const float4*)(xq);
        const float4 v1 = *(const float4*)(xq + 4);
        u32* d = (u32*)st[lg][0];
        d[xo] = pkh2(v0.x, v0.y); d[xo+1] = pkh2(v0.z, v0.w);
        d[xo+2] = pkh2(v1.x, v1.y); d[xo+3] = pkh2(v1.z, v1.w);
        xr0 = *(const float4*)(xq + IN_);
        xr1 = *(const float4*)(xq + IN_ + 4);
    }
    __syncthreads();                                   // x(0) ready

    for (int t = 0; t < T_; ++t) {
        const int cur = t & 1, nxt = cur ^ 1;

        if (comp) {
            // ---------------- group A (batches 0..15) ----------------
            const _Float16* scA_ = st[0][cur];
            const half8 Ba0 = *(const half8*)(scA_ + brow);
            const half8 Ba1 = *(const half8*)(scA_ + brow + 32);
            const u32   hTa = ((const u32*)scA_)[trow];
            // ---------------- group B (batches 16..31) ---------------
            const _Float16* scB_ = st[1][cur];
            const half8 Bb0 = *(const half8*)(scB_ + brow);
            const half8 Bb1 = *(const half8*)(scB_ + brow + 32);
            const u32   hTb = ((const u32*)scB_)[trow];

            f32x4 Ca = MFMA(A0, Ba0, bias);
            f32x4 Cb = MFMA(A0, Bb0, bias);
            Ca = MFMA(A1, Ba1, Ca);
            Cb = MFMA(A1, Bb1, Cb);
            Ca[0] = FDOT2(hTa, wt0, Ca[0]);  Cb[0] = FDOT2(hTb, wt0, Cb[0]);
            Ca[1] = FDOT2(hTa, wt1, Ca[1]);  Cb[1] = FDOT2(hTb, wt1, Cb[1]);
            Ca[2] = FDOT2(hTa, wt2, Ca[2]);  Cb[2] = FDOT2(hTb, wt2, Cb[2]);
            Ca[3] = FDOT2(hTa, wt3, Ca[3]);  Cb[3] = FDOT2(hTb, wt3, Cb[3]);

            // two independent activation chains (fills trans-latency shadows)
            const float ia = SIGS(Ca[0]), fa = SIGS(Ca[1]);
            const float ib = SIGS(Cb[0]), fb = SIGS(Cb[1]);
            const float ga = TANHS(Ca[2]), oa = SIGS(Ca[3]);
            const float gb = TANHS(Cb[2]), ob = SIGS(Cb[3]);
            cA = fmaf(fa, cA, ia * ga);
            cB = fmaf(fb, cB, ib * gb);
            const float ha = oa * TANHS(cA * (-2.0f * L2E_));
            const float hb = ob * TANHS(cB * (-2.0f * L2E_));
            if (u < HID_) {
                st[0][nxt][hrow] = (_Float16)ha;
                st[1][nxt][hrow] = (_Float16)hb;
            }
        } else {
            if (t + 1 < T_) {      // x(t+1) from regs into the nxt buffer
                u32* d = (u32*)st[lg][nxt];
                d[xo] = pkh2(xr0.x, xr0.y); d[xo+1] = pkh2(xr0.z, xr0.w);
                d[xo+2] = pkh2(xr1.x, xr1.y); d[xo+3] = pkh2(xr1.z, xr1.w);
            }
            if (t + 2 < T_) {      // prefetch x(t+2)
                xr0 = *(const float4*)(xq + (size_t)(t + 2) * IN_);
                xr1 = *(const float4*)(xq + (size_t)(t + 2) * IN_ + 4);
            }
        }
        __syncthreads();           // ONE barrier per step (32 batches)
    }

    // final h in buf 0 of each group (t=127 wrote nxt=0), fp16 rows 16..65
    // ---- FC head: 32 batches x 20 classes (640 threads, one pass)
    if (tid < BPB_ * NCLS_) {
        const int b  = tid / NCLS_;
        const int cl = tid - b * NCLS_;
        const _Float16* hf = st[b >> 4][0];
        const int bc = b & 15;
        float acc = b_fc[cl];
        #pragma unroll
        for (int j = 0; j < HID_; ++j) {
            const float hv = fmaxf((float)hf[bc * KP_ + IN_ + j], 0.0f);  // relu
            acc = fmaf(hv, W_fc[cl * HID_ + j], acc);
        }
        out[(size_t)(b0 + b) * NCLS_ + cl] = acc;
    }
}

extern "C" void kernel_launch(void* const* d_in, const int* in_sizes, int n_in,
                              void* d_out, int out_size, void* d_ws, size_t ws_size,
                              hipStream_t stream) {
    const float* x    = (const float*)d_in[0];
    const float* W_ih = (const float*)d_in[1];
    const float* W_hh = (const float*)d_in[2];
    const float* b_ih = (const float*)d_in[3];
    const float* b_hh = (const float*)d_in[4];
    const float* W_fc = (const float*)d_in[5];
    const float* b_fc = (const float*)d_in[6];
    float* out = (float*)d_out;

    const int B = in_sizes[0] / (T_ * IN_);   // 8192
    dim3 grid(B / BPB_), block(NTHR_);
    hipLaunchKernelGGL(lstm_mfma, grid, block, 0, stream,
                       x, W_ih, W_hh, b_ih, b_hh, W_fc, b_fc, out);
}

// Round 15
// 99.001 us; speedup vs baseline: 1.8086x; 1.0897x over previous
//
#include <hip/hip_runtime.h>

#define IN_    16
#define HID_   50
#define T_     128
#define NCLS_  20
#define BPB_   16     // batches per block = MFMA N
#define NTHR_  512    // 8 waves: 7 compute (2 M-tiles each) + 1 x-loader
#define KP_    96     // state row stride in halves: 16 x + 50 h + 1 bias + 29 pad
#define KPW_   48     // stride in u32

typedef _Float16 half8 __attribute__((ext_vector_type(8)));
typedef float    f32x4 __attribute__((ext_vector_type(4)));
typedef unsigned int u32;

#define L2E_ 1.4426950408889634f
__device__ __forceinline__ u32 pkh2(float a, float b) {
    union { u32 v; _Float16 h[2]; } p; p.h[0] = (_Float16)a; p.h[1] = (_Float16)b; return p.v;
}
#define MFMA(A, B, C) __builtin_amdgcn_mfma_f32_16x16x32_f16((A), (B), (C), 0, 0, 0)
// activation-domain helpers (weights/bias PRE-SCALED by -log2e / -2log2e)
#define SIGS(v)  __builtin_amdgcn_rcpf(1.0f + __builtin_amdgcn_exp2f(v))
#define TANHS(v) fmaf(2.0f, __builtin_amdgcn_rcpf(1.0f + __builtin_amdgcn_exp2f(v)), -1.0f)

// A-fragment slice from GLOBAL (R14 lesson: global-sourced frags get pinned in
// VGPRs; LDS-sourced ones get sunk back into the loop — R13's failure).
// K layout: 0..15 = x rows (W_ih), 16..65 = h rows (W_hh), 66 = bias row, rest 0.
__device__ __forceinline__ half8 load_afrag(const float* __restrict__ W_ih,
                                            const float* __restrict__ W_hh,
                                            const float* __restrict__ b_ih,
                                            const float* __restrict__ b_hh,
                                            int s, int c, int q) {
    half8 r = {};
    const int u = s >> 2, kk = s & 3;
    if (u < HID_) {
        const float sc = (kk == 2) ? (-2.0f * L2E_) : (-L2E_);
        const int g = kk * HID_ + u;
        #pragma unroll
        for (int e = 0; e < 8; ++e) {
            const int k = c * 32 + q * 8 + e;
            float w = 0.f;
            if (k < IN_)                 w = W_ih[g * IN_ + k];
            else if (k < IN_ + HID_)     w = W_hh[g * HID_ + (k - IN_)];
            else if (k == IN_ + HID_)    w = b_ih[g] + b_hh[g];     // bias row
            r[e] = (_Float16)(w * sc);
        }
    }
    return r;
}

// (512, 4 waves/EU) -> 128-VGPR cap: ~65-reg demand fits with headroom; avoids
// the R12 64-cap spill and the R5 occupancy-chase. 2 blocks/CU (grid 512).
__global__ __launch_bounds__(NTHR_, 4)
void lstm_mfma(const float* __restrict__ x,
               const float* __restrict__ W_ih,
               const float* __restrict__ W_hh,
               const float* __restrict__ b_ih,
               const float* __restrict__ b_hh,
               const float* __restrict__ W_fc,
               const float* __restrict__ b_fc,
               float* __restrict__ out)
{
    // ONLY state in LDS (no weight staging): st[buf][batch*KP_ + k]
    __shared__ __align__(16) _Float16 st[2][BPB_ * KP_];   // 6 KB

    const int tid  = threadIdx.x;
    const int lane = tid & 63;
    const int wv   = tid >> 6;          // 0..7
    const int b0   = blockIdx.x * BPB_;
    const bool comp = (wv < 7);

    // ---- init state: zeros everywhere; row 66 = 1.0h (bias row, BOTH buffers,
    //      never rewritten). h(0)=0; pad rows stay 0 forever.
    for (int idx = tid; idx < 2 * BPB_ * KPW_; idx += NTHR_)
        ((u32*)st)[idx] = ((idx % KPW_) == 33) ? 0x00003C00u : 0u;  // halves 66,67

    // ---- A-fragments: 2 tiles x 3 K-chunks from global -> 6 half8 (24 VGPRs)
    const int q  = lane >> 4;
    const int s0 = 2 * wv * 16 + (lane & 15);    // tile 2wv   slot
    const int s1 = s0 + 16;                      // tile 2wv+1 slot
    half8 A00 = {}, A01 = {}, A02 = {}, A10 = {}, A11 = {}, A12 = {};
    if (comp) {
        A00 = load_afrag(W_ih, W_hh, b_ih, b_hh, s0, 0, q);
        A01 = load_afrag(W_ih, W_hh, b_ih, b_hh, s0, 1, q);
        A02 = load_afrag(W_ih, W_hh, b_ih, b_hh, s0, 2, q);
        A10 = load_afrag(W_ih, W_hh, b_ih, b_hh, s1, 0, q);
        A11 = load_afrag(W_ih, W_hh, b_ih, b_hh, s1, 1, q);
        A12 = load_afrag(W_ih, W_hh, b_ih, b_hh, s1, 2, q);
    }

    // per-lane units (C/D row = q*4+reg -> unit q of each tile owns i,f,g,o)
    const int u0 = 8 * wv + q;          // tile 2wv units
    const int u1 = u0 + 4;              // tile 2wv+1 units
    float c0_ = 0.f, c1_ = 0.f;

    const int bcol  = lane & 15;
    const int brow  = bcol * KP_ + q * 8;          // B-frag half index (chunk 0)
    const int hrow0 = bcol * KP_ + IN_ + u0;
    const int hrow1 = bcol * KP_ + IN_ + u1;

    // ---- loader wave (wv==7): 64 lanes = 16 batches x 4 feature-quads
    const int lb = lane >> 2, fq = lane & 3;
    const float* xq = x + (size_t)(b0 + lb) * (T_ * IN_) + 4 * fq;
    const int xo = lb * KPW_ + 2 * fq;             // u32 index

    float4 xr = {0.f, 0.f, 0.f, 0.f};
    __syncthreads();                               // init visible
    if (!comp) {                                   // x(0) -> LDS, x(1) -> regs
        const float4 v = *(const float4*)xq;
        u32* d = (u32*)st[0];
        d[xo] = pkh2(v.x, v.y); d[xo + 1] = pkh2(v.z, v.w);
        xr = *(const float4*)(xq + IN_);
    }
    __syncthreads();                               // x(0) ready

    for (int t = 0; t < T_; ++t) {
        const _Float16* sc = st[t & 1];
        _Float16*       sn = st[(t & 1) ^ 1];

        if (comp) {
            const half8 B0 = *(const half8*)(sc + brow);
            const half8 B1 = *(const half8*)(sc + brow + 32);
            const half8 B2 = *(const half8*)(sc + brow + 64);
            const f32x4 Z = {0.f, 0.f, 0.f, 0.f};
            f32x4 C0 = MFMA(A00, B0, Z);
            f32x4 C1 = MFMA(A10, B0, Z);
            C0 = MFMA(A01, B1, C0);
            C1 = MFMA(A11, B1, C1);
            C0 = MFMA(A02, B2, C0);    // chunk 2 carries h-tails + bias row
            C1 = MFMA(A12, B2, C1);

            {   // tile 2wv : unit u0
                const float iv = SIGS(C0[0]), fv = SIGS(C0[1]);
                const float gv = TANHS(C0[2]), ov = SIGS(C0[3]);
                c0_ = fmaf(fv, c0_, iv * gv);
                const float hv = ov * TANHS(c0_ * (-2.0f * L2E_));
                if (u0 < HID_) sn[hrow0] = (_Float16)hv;
            }
            {   // tile 2wv+1 : unit u1
                const float iv = SIGS(C1[0]), fv = SIGS(C1[1]);
                const float gv = TANHS(C1[2]), ov = SIGS(C1[3]);
                c1_ = fmaf(fv, c1_, iv * gv);
                const float hv = ov * TANHS(c1_ * (-2.0f * L2E_));
                if (u1 < HID_) sn[hrow1] = (_Float16)hv;
            }
        } else {
            if (t + 1 < T_) {          // x(t+1) from regs (latency off-chain)
                u32* d = (u32*)sn;
                d[xo] = pkh2(xr.x, xr.y); d[xo + 1] = pkh2(xr.z, xr.w);
            }
            if (t + 2 < T_) xr = *(const float4*)(xq + (size_t)(t + 2) * IN_);
        }
        __syncthreads();               // ONE barrier per step
    }

    // final h in st[0] (t=127 wrote nxt=0), fp16 rows 16..65
    const _Float16* hf = st[0];

    // ---- FC head: 16 batches x 20 classes (320 threads)
    if (tid < BPB_ * NCLS_) {
        const int b  = tid / NCLS_;
        const int cl = tid - b * NCLS_;
        float acc = b_fc[cl];
        #pragma unroll
        for (int j = 0; j < HID_; ++j) {
            const float hv = fmaxf((float)hf[b * KP_ + IN_ + j], 0.0f);  // relu
            acc = fmaf(hv, W_fc[cl * HID_ + j], acc);
        }
        out[(size_t)(b0 + b) * NCLS_ + cl] = acc;
    }
}

extern "C" void kernel_launch(void* const* d_in, const int* in_sizes, int n_in,
                              void* d_out, int out_size, void* d_ws, size_t ws_size,
                              hipStream_t stream) {
    const float* x    = (const float*)d_in[0];
    const float* W_ih = (const float*)d_in[1];
    const float* W_hh = (const float*)d_in[2];
    const float* b_ih = (const float*)d_in[3];
    const float* b_hh = (const float*)d_in[4];
    const float* W_fc = (const float*)d_in[5];
    const float* b_fc = (const float*)d_in[6];
    float* out = (float*)d_out;

    const int B = in_sizes[0] / (T_ * IN_);   // 8192
    dim3 grid(B / BPB_), block(NTHR_);
    hipLaunchKernelGGL(lstm_mfma, grid, block, 0, stream,
                       x, W_ih, W_hh, b_ih, b_hh, W_fc, b_fc, out);
}